// Round 12
// baseline (26.043 us; speedup 1.0000x reference)
//
#include <hip/hip_runtime.h>
#include <hip/hip_bf16.h>
#include <math.h>

#define NC 16
#define B_LUT 256
#define EPT 16   // float4s per thread (64 KB contiguous chunk per block)

typedef float nfloat4 __attribute__((ext_vector_type(4)));  // native vec for nt-store

// W_hard = center[argmin_m |x - center[m]|]  (STE forward; absmax 0, R1-R11).
//
// R12 = R11 with ONE change: chunk 32 KB -> 64 KB (EPT 8 -> 16, 1024 blocks
// = exactly 4 blocks/CU). R11 confirmed DRAM-row locality as the limiter
// (block-contiguous chunks: 27.9 -> 25.4us). Bigger chunks: half the
// per-block overhead (LUT build + 2 barriers + ramp), 2x longer row streaks,
// 256B/thread in flight (MLP=16 loads issued before the LUT build).
//
// Pair-LUT in LDS, built cooperatively:
//   phase 1: threads 0..15 stable-rank-sort centers (value, tie by original
//            index) into ssort/sidx.
//   phase 2: each thread builds one bucket: k0 = #mid < bstart-g,
//            k1 = #mid < bend+g, cnt = k1-k0. cnt==0 -> (s[k0],s[k0]);
//            cnt==1 -> pair ordered by ORIGINAL index; cnt>=2 -> NaN.
// Decision r = fl(|x-cB|) < fl(|x-cA|) ? cB : cA is numpy's argmin restricted
// to the bracketing pair (bit-identical fp32 ops); validity margin ~0.039*w
// ~ 1e-3 vs fp32 rounding ~1.4e-6. Ties -> cA = lower original index =
// numpy first-min. NaN-touched waves -> bit-exact original-order scan.
// nt stores: out is write-once/never-read (R10 A/B: nt = -1.1us).

__device__ __forceinline__ float4 exact4(const float4 v,
                                         const float* __restrict__ center)
{
    float xs[4] = {v.x, v.y, v.z, v.w};
    float r[4];
#pragma unroll
    for (int j = 0; j < 4; ++j) {
        float xv = xs[j];
        float best = fabsf(xv - center[0]);
        float bc = center[0];
#pragma unroll
        for (int m = 1; m < NC; ++m) {
            float d = fabsf(xv - center[m]);
            bool lt = d < best;             // strict '<': first-min wins
            best = lt ? d : best;
            bc = lt ? center[m] : bc;
        }
        r[j] = bc;
    }
    return make_float4(r[0], r[1], r[2], r[3]);
}

__global__ void __launch_bounds__(256) quantizer_kernel(
    const float* __restrict__ x,
    const float* __restrict__ center,
    float* __restrict__ out)
{
    __shared__ __align__(16) float2 slut[B_LUT];   // 2 KB
    __shared__ float ssort[NC];
    __shared__ int   sidx[NC];

    const float4* __restrict__ x4 = reinterpret_cast<const float4*>(x);
    float4* __restrict__ o4 = reinterpret_cast<float4*>(out);
    nfloat4* __restrict__ o4n = reinterpret_cast<nfloat4*>(out);

    // Block-contiguous chunk: 4096 float4s (64 KB) per block.
    int base = blockIdx.x * (256 * EPT) + (int)threadIdx.x;

    // Issue all 16 independent stream loads NOW; they fly during the build.
    float4 v[EPT];
#pragma unroll
    for (int k = 0; k < EPT; ++k) v[k] = x4[base + k * 256];

    // ---- phase 1: 16-thread stable rank sort ------------------------------
    if (threadIdx.x < NC) {
        int t = (int)threadIdx.x;
        float c = center[t];
        int rank = 0;
#pragma unroll
        for (int m = 0; m < NC; ++m) {
            float cm = center[m];
            rank += (cm < c || (cm == c && m < t)) ? 1 : 0;
        }
        ssort[rank] = c;
        sidx[rank] = t;
    }
    __syncthreads();

    // ---- phase 2: one bucket per thread, from broadcast LDS reads ---------
    float s0 = ssort[0], s15 = ssort[NC - 1];
    float span = s15 - s0;
    if (!(span > 0.f)) span = 1.f;          // degenerate: all-equal centers
    float w = span * (1.0f / 256.0f);
    float invw = 256.0f / span;
    float nb = -s0 * invw;                  // ft = fma(x, invw, nb)

    {
        int t = (int)threadIdx.x;
        float bstart = s0 + t * w;
        float g = 0.02f * w;                // >> fma/cvt routing slop (~3e-4*w)
        float lo_th = bstart - g;
        float hi_th = bstart + w + g;

        int k0 = 0, k1 = 0;
        float sp = s0;
#pragma unroll
        for (int j = 0; j < NC - 1; ++j) {
            float sn = ssort[j + 1];        // broadcast read
            float mid = 0.5f * (sp + sn);
            k0 += (mid < lo_th) ? 1 : 0;
            k1 += (mid < hi_th) ? 1 : 0;
            sp = sn;
        }
        int cnt = k1 - k0;

        float ca, cb;
        if (cnt == 0) {
            float ck = ssort[k0];           // dynamic LDS read
            ca = ck; cb = ck;
        } else if (cnt == 1) {
            float a = ssort[k0], b = ssort[k0 + 1];
            int ia = sidx[k0], ib = sidx[k0 + 1];
            bool sw = ib < ia;              // order pair by ORIGINAL index
            ca = sw ? b : a;
            cb = sw ? a : b;
        } else {
            ca = __uint_as_float(0x7fc00000u);  // NaN sentinel -> wave fallback
            cb = 0.f;
        }
        slut[t] = make_float2(ca, cb);
    }
    __syncthreads();
    // -----------------------------------------------------------------------

    bool bad = false;
#pragma unroll
    for (int k = 0; k < EPT; ++k) {
        float xs[4] = {v[k].x, v[k].y, v[k].z, v[k].w};
        float r[4];
#pragma unroll
        for (int j = 0; j < 4; ++j) {
            float ft = fmaf(xs[j], invw, nb);
            ft = __builtin_amdgcn_fmed3f(ft, 0.f, (float)(B_LUT - 1));
            int t = (int)ft;
            float2 e = slut[t];             // random ds_read_b64, 2KB table
            float da = fabsf(xs[j] - e.x);  // exact numpy ops on the pair
            float db = fabsf(xs[j] - e.y);
            r[j] = (db < da) ? e.y : e.x;   // strict: tie -> cA (lower index)
            bad |= (e.x != e.x);            // NaN sentinel
        }
        // Nontemporal: out is write-once/never-read.
        __builtin_nontemporal_store((nfloat4){r[0], r[1], r[2], r[3]},
                                    &o4n[base + k * 256]);
    }

    if (__any(bad)) {
        // Cold path: reload x, recompute all 64 bit-exactly, overwrite.
        // Same-thread same-address stores are program-ordered.
#pragma unroll
        for (int k = 0; k < EPT; ++k)
            o4[base + k * 256] = exact4(x4[base + k * 256], center);
    }
}

extern "C" void kernel_launch(void* const* d_in, const int* in_sizes, int n_in,
                              void* d_out, int out_size, void* d_ws, size_t ws_size,
                              hipStream_t stream) {
    const float* x      = (const float*)d_in[0];
    const float* center = (const float*)d_in[1];
    float* out          = (float*)d_out;

    int n = in_sizes[0];          // 16*64*128*128 = 16,777,216
    int n4 = n / 4;               // 4,194,304 float4s

    const int block = 256;
    int grid = n4 / (block * EPT);   // 1024 blocks, contiguous 64KB chunks
    quantizer_kernel<<<grid, block, 0, stream>>>(x, center, out);
}

// Round 13
// 25.293 us; speedup vs baseline: 1.0297x; 1.0297x over previous
//
#include <hip/hip_runtime.h>
#include <hip/hip_bf16.h>
#include <math.h>

#define NC 16
#define B_LUT 256
#define EPT 8   // float4s per thread (32 KB contiguous chunk per block)

// W_hard = center[argmin_m |x - center[m]|]  (STE forward; absmax 0, R1-R12).
//
// R13 = R11 with ONE change: plain stores instead of nontemporal. R10's
// "nt wins 1.1us" A/B predates the block-contiguous addressing (R11); under
// contiguous 32KB chunks, plain stores aggregate in L2 per-block and allow
// the full 134MB working set (x 67 + out 67 < 256MB L3) to stay L3-resident
// across graph replays (nt write-through forfeits this). Single-variable A/B.
//
// Pair-LUT in LDS, built cooperatively:
//   phase 1: threads 0..15 stable-rank-sort centers (value, tie by original
//            index) into ssort/sidx.
//   phase 2: each thread builds one bucket: k0 = #mid < bstart-g,
//            k1 = #mid < bend+g, cnt = k1-k0. cnt==0 -> (s[k0],s[k0]);
//            cnt==1 -> pair ordered by ORIGINAL index; cnt>=2 -> NaN.
// Decision r = fl(|x-cB|) < fl(|x-cA|) ? cB : cA is numpy's argmin restricted
// to the bracketing pair (bit-identical fp32 ops); validity margin ~0.039*w
// ~ 1e-3 vs fp32 rounding ~1.4e-6. Ties -> cA = lower original index =
// numpy first-min. NaN-touched waves -> bit-exact original-order scan.

__device__ __forceinline__ float4 exact4(const float4 v,
                                         const float* __restrict__ center)
{
    float xs[4] = {v.x, v.y, v.z, v.w};
    float r[4];
#pragma unroll
    for (int j = 0; j < 4; ++j) {
        float xv = xs[j];
        float best = fabsf(xv - center[0]);
        float bc = center[0];
#pragma unroll
        for (int m = 1; m < NC; ++m) {
            float d = fabsf(xv - center[m]);
            bool lt = d < best;             // strict '<': first-min wins
            best = lt ? d : best;
            bc = lt ? center[m] : bc;
        }
        r[j] = bc;
    }
    return make_float4(r[0], r[1], r[2], r[3]);
}

__global__ void __launch_bounds__(256) quantizer_kernel(
    const float* __restrict__ x,
    const float* __restrict__ center,
    float* __restrict__ out)
{
    __shared__ __align__(16) float2 slut[B_LUT];   // 2 KB
    __shared__ float ssort[NC];
    __shared__ int   sidx[NC];

    const float4* __restrict__ x4 = reinterpret_cast<const float4*>(x);
    float4* __restrict__ o4 = reinterpret_cast<float4*>(out);

    // Block-contiguous chunk: 2048 float4s (32 KB) per block.
    int base = blockIdx.x * (256 * EPT) + (int)threadIdx.x;

    // Issue all 8 independent stream loads NOW; they fly during the build.
    float4 v[EPT];
#pragma unroll
    for (int k = 0; k < EPT; ++k) v[k] = x4[base + k * 256];

    // ---- phase 1: 16-thread stable rank sort ------------------------------
    if (threadIdx.x < NC) {
        int t = (int)threadIdx.x;
        float c = center[t];
        int rank = 0;
#pragma unroll
        for (int m = 0; m < NC; ++m) {
            float cm = center[m];
            rank += (cm < c || (cm == c && m < t)) ? 1 : 0;
        }
        ssort[rank] = c;
        sidx[rank] = t;
    }
    __syncthreads();

    // ---- phase 2: one bucket per thread, from broadcast LDS reads ---------
    float s0 = ssort[0], s15 = ssort[NC - 1];
    float span = s15 - s0;
    if (!(span > 0.f)) span = 1.f;          // degenerate: all-equal centers
    float w = span * (1.0f / 256.0f);
    float invw = 256.0f / span;
    float nb = -s0 * invw;                  // ft = fma(x, invw, nb)

    {
        int t = (int)threadIdx.x;
        float bstart = s0 + t * w;
        float g = 0.02f * w;                // >> fma/cvt routing slop (~3e-4*w)
        float lo_th = bstart - g;
        float hi_th = bstart + w + g;

        int k0 = 0, k1 = 0;
        float sp = s0;
#pragma unroll
        for (int j = 0; j < NC - 1; ++j) {
            float sn = ssort[j + 1];        // broadcast read
            float mid = 0.5f * (sp + sn);
            k0 += (mid < lo_th) ? 1 : 0;
            k1 += (mid < hi_th) ? 1 : 0;
            sp = sn;
        }
        int cnt = k1 - k0;

        float ca, cb;
        if (cnt == 0) {
            float ck = ssort[k0];           // dynamic LDS read
            ca = ck; cb = ck;
        } else if (cnt == 1) {
            float a = ssort[k0], b = ssort[k0 + 1];
            int ia = sidx[k0], ib = sidx[k0 + 1];
            bool sw = ib < ia;              // order pair by ORIGINAL index
            ca = sw ? b : a;
            cb = sw ? a : b;
        } else {
            ca = __uint_as_float(0x7fc00000u);  // NaN sentinel -> wave fallback
            cb = 0.f;
        }
        slut[t] = make_float2(ca, cb);
    }
    __syncthreads();
    // -----------------------------------------------------------------------

    bool bad = false;
#pragma unroll
    for (int k = 0; k < EPT; ++k) {
        float xs[4] = {v[k].x, v[k].y, v[k].z, v[k].w};
        float r[4];
#pragma unroll
        for (int j = 0; j < 4; ++j) {
            float ft = fmaf(xs[j], invw, nb);
            ft = __builtin_amdgcn_fmed3f(ft, 0.f, (float)(B_LUT - 1));
            int t = (int)ft;
            float2 e = slut[t];             // random ds_read_b64, 2KB table
            float da = fabsf(xs[j] - e.x);  // exact numpy ops on the pair
            float db = fabsf(xs[j] - e.y);
            r[j] = (db < da) ? e.y : e.x;   // strict: tie -> cA (lower index)
            bad |= (e.x != e.x);            // NaN sentinel
        }
        o4[base + k * 256] = make_float4(r[0], r[1], r[2], r[3]);  // plain store
    }

    if (__any(bad)) {
        // Cold path: reload x, recompute all 32 bit-exactly, overwrite.
        // Same-thread same-address stores are program-ordered.
#pragma unroll
        for (int k = 0; k < EPT; ++k)
            o4[base + k * 256] = exact4(x4[base + k * 256], center);
    }
}

extern "C" void kernel_launch(void* const* d_in, const int* in_sizes, int n_in,
                              void* d_out, int out_size, void* d_ws, size_t ws_size,
                              hipStream_t stream) {
    const float* x      = (const float*)d_in[0];
    const float* center = (const float*)d_in[1];
    float* out          = (float*)d_out;

    int n = in_sizes[0];          // 16*64*128*128 = 16,777,216
    int n4 = n / 4;               // 4,194,304 float4s

    const int block = 256;
    int grid = n4 / (block * EPT);   // 2048 blocks, contiguous 32KB chunks
    quantizer_kernel<<<grid, block, 0, stream>>>(x, center, out);
}